// Round 11
// baseline (312.011 us; speedup 1.0000x reference)
//
#include <hip/hip_runtime.h>
#include <hip/hip_bf16.h>
#include <stdint.h>

typedef __attribute__((ext_vector_type(4))) float f32x4;
typedef __attribute__((ext_vector_type(8))) short short8;
typedef unsigned int u32;
typedef unsigned short ushort_t;

#define L_DIM 2048
#define B_DIM 32
#define D_DIM 512
#define M_DIM (L_DIM * B_DIM)       // 65536
#define N_DIM (3 * D_DIM)           // 1536
#define K_DIM D_DIM                 // 512
#define BD    (B_DIM * D_DIM)       // 16384
#define PLANE ((size_t)M_DIM * D_DIM)  // 33554432 elems per U plane
#define CHUNK 32
#define NCHUNK (L_DIM / CHUNK)      // 64
#define LOG2E 1.4426950408889634f

// ---------- helpers ----------
__device__ inline ushort_t f2bf(float f) {
    uint32_t u = __float_as_uint(f);
    u += 0x7FFFu + ((u >> 16) & 1u);   // RNE
    return (ushort_t)(u >> 16);
}
__device__ inline float b2f(ushort_t h) {
    return __uint_as_float(((uint32_t)h) << 16);
}
__device__ inline float exp2_hw(float x) {
    float r;
    asm("v_exp_f32 %0, %1" : "=v"(r) : "v"(x));
    return r;
}
__device__ inline void gll16(const ushort_t* g, ushort_t* l) {
    __builtin_amdgcn_global_load_lds(
        (const __attribute__((address_space(1))) u32*)g,
        (__attribute__((address_space(3))) u32*)l,
        16, 0, 0);
}

// ---------- kernel 1: x (f32) -> xb (bf16) ----------
__global__ void k_convert_x(const float4* __restrict__ x, ushort4* __restrict__ xb) {
    int i = blockIdx.x * blockDim.x + threadIdx.x;
    int stride = gridDim.x * blockDim.x;
    const int n4 = M_DIM * D_DIM / 4;   // 8388608
    for (; i < n4; i += stride) {
        float4 v = x[i];
        ushort4 o;
        o.x = f2bf(v.x); o.y = f2bf(v.y); o.z = f2bf(v.z); o.w = f2bf(v.w);
        xb[i] = o;
    }
}

// ---------- kernel 2: weight (D,3D) f32 -> wt [N][K] bf16, gate-deinterleaved ----------
__global__ void k_prep_w(const float* __restrict__ w, ushort_t* __restrict__ wt) {
    int idx = blockIdx.x * blockDim.x + threadIdx.x;
    if (idx >= N_DIM * K_DIM) return;
    int k = idx & 511;
    int n = idx >> 9;
    int dcol = (n & 511) * 3 + (n >> 9);
    wt[idx] = f2bf(w[(size_t)k * N_DIM + dcol]);
}

// ---------- kernel 3: GEMM 128M x 256N tile, 4 waves (each 64M x 128N) ------
// Same verified dataflow as round-3 (gll16 + XOR swizzle + syncthreads),
// doubled per-wave acc (f32x4[4][8]=128 VGPR) -> LDS/L2 bytes per MFMA-cycle
// drop ~25% (the measured 27% MfmaUtil cap). Prescaled gate planes as round-10.
__global__ __launch_bounds__(256) void k_gemm(
    const ushort_t* __restrict__ Ag,   // [M,K] bf16
    const ushort_t* __restrict__ Wt,   // [N,K] bf16
    const float*    __restrict__ bias, // [2D]
    ushort_t*       __restrict__ U)    // 3 planes of [M,D] bf16
{
    __shared__ ushort_t As[128 * 64];   // 16 KB
    __shared__ ushort_t Bs[256 * 64];   // 32 KB
    const int tid  = threadIdx.x;
    const int lane = tid & 63;
    const int w    = tid >> 6;
    const int wm   = w >> 1, wn = w & 1;

    // XCD-chunked swizzle: 3072 blocks, 8 XCDs, 384 per XCD (bijective).
    const int i   = blockIdx.x;
    const int nb  = (i & 7) * 384 + (i >> 3);
    const int bx  = nb % 6;              // N tile (innermost -> A reuse)
    const int by  = nb / 6;              // M strip
    const int bn0 = bx * 256;
    const int bm0 = by * 128;

    f32x4 acc[4][8] = {};

    for (int kt = 0; kt < K_DIM / 64; ++kt) {
        if (kt) __syncthreads();
        // A: 1024 chunks (128 rows x 8), B: 2048 chunks (256 rows x 8)
#pragma unroll
        for (int it = 0; it < 4; ++it) {
            int c   = it * 256 + tid;
            int row = c >> 3;
            int cin = (c & 7) ^ (row & 7);
            const ushort_t* ga = Ag + (size_t)(bm0 + row) * K_DIM + kt * 64 + cin * 8;
            int chunkbase = it * 256 + w * 64;   // wave-uniform
            gll16(ga, As + chunkbase * 8);
        }
#pragma unroll
        for (int it = 0; it < 8; ++it) {
            int c   = it * 256 + tid;
            int row = c >> 3;
            int cin = (c & 7) ^ (row & 7);
            const ushort_t* gb = Wt + (size_t)(bn0 + row) * K_DIM + kt * 64 + cin * 8;
            int chunkbase = it * 256 + w * 64;   // wave-uniform
            gll16(gb, Bs + chunkbase * 8);
        }
        __syncthreads();
#pragma unroll
        for (int kk = 0; kk < 2; ++kk) {
            short8 af[4], bfr[8];
#pragma unroll
            for (int m = 0; m < 4; ++m) {
                int row  = wm * 64 + m * 16 + (lane & 15);
                int byte = (row * 128 + kk * 64 + ((lane >> 4) * 16)) ^ ((row & 7) << 4);
                af[m] = *(const short8*)((const char*)As + byte);
            }
#pragma unroll
            for (int n = 0; n < 8; ++n) {
                int row  = wn * 128 + n * 16 + (lane & 15);
                int byte = (row * 128 + kk * 64 + ((lane >> 4) * 16)) ^ ((row & 7) << 4);
                bfr[n] = *(const short8*)((const char*)Bs + byte);
            }
#pragma unroll
            for (int m = 0; m < 4; ++m)
#pragma unroll
                for (int n = 0; n < 8; ++n)
                    acc[m][n] = __builtin_amdgcn_mfma_f32_16x16x32_bf16(
                        af[m], bfr[n], acc[m][n], 0, 0, 0);
        }
    }

    // epilogue: C/D layout col=lane&15, row=(lane>>4)*4+q (m89-verified)
    const int g  = bn0 >> 9;               // plane (256-wide tile stays in one plane)
    const int db = (bn0 & 511) + wn * 128; // d base in plane
    const float sgn = g ? -LOG2E : 1.0f;   // prescale gate planes
    ushort_t* Up = U + (size_t)g * PLANE;
#pragma unroll
    for (int n = 0; n < 8; ++n) {
        int col = db + n * 16 + (lane & 15);
        float ba = 0.f;
        if (g) ba = bias[(g - 1) * 512 + col];
#pragma unroll
        for (int m = 0; m < 4; ++m) {
            int row0 = bm0 + wm * 64 + m * 16 + ((lane >> 4) * 4);
#pragma unroll
            for (int q = 0; q < 4; ++q) {
                Up[(size_t)(row0 + q) * D_DIM + col] = f2bf((acc[m][n][q] + ba) * sgn);
            }
        }
    }
}

// ---------- kernel 4: role-split scan (round-10 verified) ----------
__global__ __launch_bounds__(256) void k_scan2(
    const ushort_t* __restrict__ U,    // planes: u0 | u1n | u2n  [t*32+b][d]
    const ushort_t* __restrict__ xb,   // [t*32+b][d]
    const float*    __restrict__ wc,   // weight_c [2D]
    const float*    __restrict__ cin,  // c_init [B,D]
    float*          __restrict__ out)  // h [L,B,D] f32, then c_last [B,D]
{
    __shared__ ushort_t r01[2][2][CHUNK][64];  // u0,u1n ring (16 KB)
    __shared__ ushort_t r23[3][2][CHUNK][64];  // u2n,x ring, 3-deep (24 KB)
    __shared__ float    cr[2][CHUNK][64];      // c_new ring (16 KB)
    __shared__ float    cp0[2][64];            // chunk-incoming c (512 B)

    const int tid  = threadIdx.x;
    const int lane = tid & 63;
    const int wv   = tid >> 6;               // 0 prod, 1 chain, 2-3 finish
    const int cb   = blockIdx.x * 64;        // chain base

    const int srow = lane >> 3;
    const int scol = (lane & 7) * 8;
    const ushort_t* s0 = U + cb + scol;
    const ushort_t* s1 = U + PLANE + cb + scol;
    const ushort_t* s2 = U + 2 * PLANE + cb + scol;
    const ushort_t* s3 = xb + cb + scol;

    const int chain = cb + lane;
    const int d     = chain & 511;
    float fwn = 0.f, c = 0.f, rwn = 0.f;
    if (wv == 1) { fwn = -LOG2E * wc[d]; c = cin[chain]; }
    if (wv >= 2) { rwn = -LOG2E * wc[512 + d]; }
    float* ho = out + chain;

#define PRODUCE(CK)                                                            \
    do {                                                                       \
        const size_t t0_ = (size_t)(CK) * CHUNK + srow;                        \
        const int nb_ = (CK) & 1, nc_ = (CK) % 3;                              \
        _Pragma("unroll")                                                      \
        for (int q = 0; q < 4; ++q) {                                          \
            gll16(s0 + (t0_ + q * 8) * BD, &r01[nb_][0][q * 8][0]);            \
            gll16(s1 + (t0_ + q * 8) * BD, &r01[nb_][1][q * 8][0]);            \
            gll16(s2 + (t0_ + q * 8) * BD, &r23[nc_][0][q * 8][0]);            \
            gll16(s3 + (t0_ + q * 8) * BD, &r23[nc_][1][q * 8][0]);            \
        }                                                                      \
    } while (0)

    if (wv == 0) PRODUCE(0);
    __syncthreads();

    for (int ck = 0; ck <= NCHUNK; ++ck) {
        if (wv == 0) {
            if (ck + 1 < NCHUNK) PRODUCE(ck + 1);
        } else if (wv == 1) {
            if (ck < NCHUNK) {
                const int b = ck & 1;
                cp0[b][lane] = c;            // incoming c for this chunk
#pragma unroll
                for (int s = 0; s < CHUNK; ++s) {
                    float u0  = b2f(r01[b][0][s][lane]);
                    float u1n = b2f(r01[b][1][s][lane]);
                    float f = __builtin_amdgcn_rcpf(
                        1.f + exp2_hw(fmaf(c, fwn, u1n)));
                    c = fmaf(c - u0, f, u0);
                    cr[b][s][lane] = c;
                }
            }
        } else {
            if (ck >= 1) {
                const int fk = ck - 1;
                const int bc = fk & 1, b3 = fk % 3;
                const int sb = (wv - 2) * 16;
                const size_t tb = (size_t)fk * CHUNK;
                float cp = (sb == 0) ? cp0[bc][lane] : cr[bc][15][lane];
#pragma unroll
                for (int s2 = 0; s2 < 16; ++s2) {
                    int s = sb + s2;
                    float cc  = cr[bc][s][lane];          // c_new at step s
                    float u2n = b2f(r23[b3][0][s][lane]);
                    float xf  = b2f(r23[b3][1][s][lane]);
                    float r = __builtin_amdgcn_rcpf(
                        1.f + exp2_hw(fmaf(cp, rwn, u2n)));   // r uses c_prev
                    ho[(tb + s) * BD] = fmaf(cc - xf, r, xf); // h uses c_new
                    cp = cc;
                }
            }
        }
        __syncthreads();
    }

    if (wv == 1) out[(size_t)L_DIM * BD + chain] = c;
}

// ---------- launch ----------
extern "C" void kernel_launch(void* const* d_in, const int* in_sizes, int n_in,
                              void* d_out, int out_size, void* d_ws, size_t ws_size,
                              hipStream_t stream) {
    const float* x      = (const float*)d_in[0];
    const float* weight = (const float*)d_in[1];
    const float* wc     = (const float*)d_in[2];
    const float* bias   = (const float*)d_in[3];
    const float* cinit  = (const float*)d_in[4];
    float* out = (float*)d_out;

    // ws layout (bf16 elems): xb[PLANE] | U0|U1n|U2n [3*PLANE] | wt[786432]
    ushort_t* ws = (ushort_t*)d_ws;
    ushort_t* xb = ws;
    ushort_t* U  = ws + PLANE;           // 3 contiguous planes
    ushort_t* wt = ws + 4 * PLANE;

    k_convert_x<<<4096, 256, 0, stream>>>((const float4*)x, (ushort4*)xb);
    k_prep_w<<<(N_DIM * K_DIM) / 256, 256, 0, stream>>>(weight, wt);
    k_gemm<<<3072, 256, 0, stream>>>(xb, wt, bias, U);
    k_scan2<<<BD / 64, 256, 0, stream>>>(U, xb, wc, cinit, out);
}

// Round 12
// 300.105 us; speedup vs baseline: 1.0397x; 1.0397x over previous
//
#include <hip/hip_runtime.h>
#include <hip/hip_bf16.h>
#include <stdint.h>

typedef __attribute__((ext_vector_type(4))) float f32x4;
typedef __attribute__((ext_vector_type(8))) short short8;
typedef unsigned int u32;
typedef unsigned short ushort_t;

#define L_DIM 2048
#define B_DIM 32
#define D_DIM 512
#define M_DIM (L_DIM * B_DIM)       // 65536
#define N_DIM (3 * D_DIM)           // 1536
#define K_DIM D_DIM                 // 512
#define BD    (B_DIM * D_DIM)       // 16384
#define PLANE ((size_t)M_DIM * D_DIM)  // 33554432 elems per U plane
#define CHUNK 32
#define NCHUNK (L_DIM / CHUNK)      // 64
#define LOG2E 1.4426950408889634f

// ---------- helpers ----------
__device__ inline ushort_t f2bf(float f) {
    uint32_t u = __float_as_uint(f);
    u += 0x7FFFu + ((u >> 16) & 1u);   // RNE
    return (ushort_t)(u >> 16);
}
__device__ inline float b2f(ushort_t h) {
    return __uint_as_float(((uint32_t)h) << 16);
}
__device__ inline float exp2_hw(float x) {
    float r;
    asm("v_exp_f32 %0, %1" : "=v"(r) : "v"(x));
    return r;
}
__device__ inline void gll16(const ushort_t* g, ushort_t* l) {
    __builtin_amdgcn_global_load_lds(
        (const __attribute__((address_space(1))) u32*)g,
        (__attribute__((address_space(3))) u32*)l,
        16, 0, 0);
}

// ---------- kernel 1: x (f32) -> xb (bf16) ----------
__global__ void k_convert_x(const float4* __restrict__ x, ushort4* __restrict__ xb) {
    int i = blockIdx.x * blockDim.x + threadIdx.x;
    int stride = gridDim.x * blockDim.x;
    const int n4 = M_DIM * D_DIM / 4;   // 8388608
    for (; i < n4; i += stride) {
        float4 v = x[i];
        ushort4 o;
        o.x = f2bf(v.x); o.y = f2bf(v.y); o.z = f2bf(v.z); o.w = f2bf(v.w);
        xb[i] = o;
    }
}

// ---------- kernel 2: weight (D,3D) f32 -> wt [N][K] bf16, gate-deinterleaved ----------
__global__ void k_prep_w(const float* __restrict__ w, ushort_t* __restrict__ wt) {
    int idx = blockIdx.x * blockDim.x + threadIdx.x;
    if (idx >= N_DIM * K_DIM) return;
    int k = idx & 511;
    int n = idx >> 9;
    int dcol = (n & 511) * 3 + (n >> 9);
    wt[idx] = f2bf(w[(size_t)k * N_DIM + dcol]);
}

// ---------- kernel 3: faithful m201-style 8-phase 256x256 GEMM ----------
// 8 waves (2M x 4N), per-wave 128x64 out (acc f32x4[8][4]=128 VGPR), BK=64,
// 128 KiB LDS dbuf. Per K-tile: 4 phases {reads||stage; bar; prio1;16 MFMA;
// prio0; bar}, vmcnt(6) once per K-tile. Stage slots obey region hazards:
//   B(t+2)h0 @ t.q2 (B[buf] reads end q1);  B(t+2)h1+A(t+2)h0 @ t.q3
//   (A[buf] reads end q2);  A(t+2)h1 @ (t+1).q0 (other buffer).
// Oldest-8 in-flight at t.q3 == tile t+1's 8 loads -> vmcnt(6) correct.
__global__ __launch_bounds__(512, 1) void k_gemm8p(
    const ushort_t* __restrict__ Ag,   // [M,K] bf16
    const ushort_t* __restrict__ Wt,   // [N,K] bf16
    const float*    __restrict__ bias, // [2D]
    ushort_t*       __restrict__ U)    // 3 planes of [M,D] bf16
{
    __shared__ ushort_t As[2][256 * 64];   // 64 KB
    __shared__ ushort_t Bs[2][256 * 64];   // 64 KB
    const int tid  = threadIdx.x;
    const int lane = tid & 63;
    const int w    = tid >> 6;      // 0..7
    const int wr   = w >> 2;        // 0..1 (M half)
    const int wc   = w & 3;         // 0..3 (N quarter)

    // XCD-chunked swizzle: 1536 blocks, 8 XCDs, 192/XCD (bijective); bx innermost
    const int i   = blockIdx.x;
    const int nb  = (i & 7) * 192 + (i >> 3);
    const int bx  = nb % 6;
    const int by  = nb / 6;
    const int bn0 = bx * 256;
    const int bm0 = by * 256;

    // staging invariants (round r: rows r*64 + (tid>>3), chunk tid&7,
    // source chunk = (tid&7) ^ (row&7); dest linear chunk = r*512 + tid)
    const int rowoff = tid >> 3;
    const int cin    = (tid & 7) ^ ((tid >> 3) & 7);
    const ushort_t* pA = Ag + (size_t)(bm0 + rowoff) * K_DIM + cin * 8;
    const ushort_t* pB = Wt + (size_t)(bn0 + rowoff) * K_DIM + cin * 8;

    f32x4  acc[8][4] = {};
    short8 af[4][2], bf[2][2][2];

#define BAR()   __builtin_amdgcn_s_barrier()
#define PRIO1() __builtin_amdgcn_s_setprio(1)
#define PRIO0() __builtin_amdgcn_s_setprio(0)
#define VM6()   asm volatile("s_waitcnt vmcnt(6)" ::: "memory")
#define VM8()   asm volatile("s_waitcnt vmcnt(8)" ::: "memory")
#define VM0()   asm volatile("s_waitcnt vmcnt(0)" ::: "memory")

#define STG_A(T, H)                                                           \
    { _Pragma("unroll")                                                       \
      for (int r = 2 * (H); r < 2 * (H) + 2; ++r)                             \
          gll16(pA + (size_t)(r * 64) * K_DIM + (size_t)(T) * 64,             \
                &As[(T) & 1][(r * 512 + w * 64) * 8]); }
#define STG_B(T, H)                                                           \
    { _Pragma("unroll")                                                       \
      for (int r = 2 * (H); r < 2 * (H) + 2; ++r)                             \
          gll16(pB + (size_t)(r * 64) * K_DIM + (size_t)(T) * 64,             \
                &Bs[(T) & 1][(r * 512 + w * 64) * 8]); }

#define RD_A(MH)                                                              \
    { _Pragma("unroll")                                                       \
      for (int mm = 0; mm < 4; ++mm)                                          \
          _Pragma("unroll")                                                   \
          for (int kk = 0; kk < 2; ++kk) {                                    \
              int row  = wr * 128 + ((MH) * 4 + mm) * 16 + (lane & 15);       \
              int byte = (row * 128 + kk * 64 + ((lane >> 4) * 16))           \
                         ^ ((row & 7) << 4);                                  \
              af[mm][kk] = *(const short8*)((const char*)&As[bufc][0] + byte);\
          } }
#define RD_B(NH)                                                              \
    { _Pragma("unroll")                                                       \
      for (int nn = 0; nn < 2; ++nn)                                          \
          _Pragma("unroll")                                                   \
          for (int kk = 0; kk < 2; ++kk) {                                    \
              int row  = wc * 64 + ((NH) * 2 + nn) * 16 + (lane & 15);        \
              int byte = (row * 128 + kk * 64 + ((lane >> 4) * 16))           \
                         ^ ((row & 7) << 4);                                  \
              bf[NH][nn][kk] = *(const short8*)((const char*)&Bs[bufc][0] + byte);\
          } }
#define MM(MH, NH)                                                            \
    { _Pragma("unroll")                                                       \
      for (int mm = 0; mm < 4; ++mm)                                          \
          _Pragma("unroll")                                                   \
          for (int nn = 0; nn < 2; ++nn)                                      \
              _Pragma("unroll")                                               \
              for (int kk = 0; kk < 2; ++kk)                                  \
                  acc[(MH) * 4 + mm][(NH) * 2 + nn] =                         \
                      __builtin_amdgcn_mfma_f32_16x16x32_bf16(                \
                          af[mm][kk], bf[NH][nn][kk],                         \
                          acc[(MH) * 4 + mm][(NH) * 2 + nn], 0, 0, 0); }

    // prologue: fully stage K-tiles 0 and 1 (16 glls); tile 0 landed; barrier
    STG_A(0, 0); STG_A(0, 1); STG_B(0, 0); STG_B(0, 1);
    STG_A(1, 0); STG_A(1, 1); STG_B(1, 0); STG_B(1, 1);
    VM8();
    BAR();

#pragma unroll
    for (int t = 0; t < 8; ++t) {
        const int bufc = t & 1;
        // phase q0: (mh0,nh0)
        RD_A(0); RD_B(0);
        if (t >= 1 && t <= 6) STG_A(t + 1, 1);
        BAR(); PRIO1(); MM(0, 0); PRIO0(); BAR();
        // phase q1: (mh0,nh1)
        RD_B(1);
        BAR(); PRIO1(); MM(0, 1); PRIO0(); BAR();
        // phase q2: (mh1,nh0)
        RD_A(1);
        if (t <= 5) STG_B(t + 2, 0);
        BAR(); PRIO1(); MM(1, 0); PRIO0(); BAR();
        // phase q3: (mh1,nh1)
        if (t <= 5) { STG_B(t + 2, 1); STG_A(t + 2, 0); }
        BAR(); PRIO1(); MM(1, 1); PRIO0();
        if (t <= 5)      VM6();
        else if (t == 6) VM0();
        BAR();
    }

#undef MM
#undef RD_A
#undef RD_B
#undef STG_A
#undef STG_B

    // epilogue: C/D layout col=lane&15, row=(lane>>4)*4+q (m89-verified)
    const int g  = bn0 >> 9;               // plane (256-tile stays inside a plane)
    const float sgn = g ? -LOG2E : 1.0f;   // prescale gate planes
    ushort_t* Up = U + (size_t)g * PLANE;
#pragma unroll
    for (int n = 0; n < 4; ++n) {
        int col = (bn0 & 511) + wc * 64 + n * 16 + (lane & 15);
        float ba = 0.f;
        if (g) ba = bias[(g - 1) * 512 + col];
#pragma unroll
        for (int m = 0; m < 8; ++m) {
            int row0 = bm0 + wr * 128 + m * 16 + ((lane >> 4) * 4);
#pragma unroll
            for (int q = 0; q < 4; ++q) {
                Up[(size_t)(row0 + q) * D_DIM + col] = f2bf((acc[m][n][q] + ba) * sgn);
            }
        }
    }
}

// ---------- kernel 4: role-split scan (round-10 verified) ----------
__global__ __launch_bounds__(256) void k_scan2(
    const ushort_t* __restrict__ U,    // planes: u0 | u1n | u2n  [t*32+b][d]
    const ushort_t* __restrict__ xb,   // [t*32+b][d]
    const float*    __restrict__ wc,   // weight_c [2D]
    const float*    __restrict__ cin,  // c_init [B,D]
    float*          __restrict__ out)  // h [L,B,D] f32, then c_last [B,D]
{
    __shared__ ushort_t r01[2][2][CHUNK][64];  // u0,u1n ring (16 KB)
    __shared__ ushort_t r23[3][2][CHUNK][64];  // u2n,x ring, 3-deep (24 KB)
    __shared__ float    cr[2][CHUNK][64];      // c_new ring (16 KB)
    __shared__ float    cp0[2][64];            // chunk-incoming c (512 B)

    const int tid  = threadIdx.x;
    const int lane = tid & 63;
    const int wv   = tid >> 6;               // 0 prod, 1 chain, 2-3 finish
    const int cb   = blockIdx.x * 64;        // chain base

    const int srow = lane >> 3;
    const int scol = (lane & 7) * 8;
    const ushort_t* s0 = U + cb + scol;
    const ushort_t* s1 = U + PLANE + cb + scol;
    const ushort_t* s2 = U + 2 * PLANE + cb + scol;
    const ushort_t* s3 = xb + cb + scol;

    const int chain = cb + lane;
    const int d     = chain & 511;
    float fwn = 0.f, c = 0.f, rwn = 0.f;
    if (wv == 1) { fwn = -LOG2E * wc[d]; c = cin[chain]; }
    if (wv >= 2) { rwn = -LOG2E * wc[512 + d]; }
    float* ho = out + chain;

#define PRODUCE(CK)                                                            \
    do {                                                                       \
        const size_t t0_ = (size_t)(CK) * CHUNK + srow;                        \
        const int nb_ = (CK) & 1, nc_ = (CK) % 3;                              \
        _Pragma("unroll")                                                      \
        for (int q = 0; q < 4; ++q) {                                          \
            gll16(s0 + (t0_ + q * 8) * BD, &r01[nb_][0][q * 8][0]);            \
            gll16(s1 + (t0_ + q * 8) * BD, &r01[nb_][1][q * 8][0]);            \
            gll16(s2 + (t0_ + q * 8) * BD, &r23[nc_][0][q * 8][0]);            \
            gll16(s3 + (t0_ + q * 8) * BD, &r23[nc_][1][q * 8][0]);            \
        }                                                                      \
    } while (0)

    if (wv == 0) PRODUCE(0);
    __syncthreads();

    for (int ck = 0; ck <= NCHUNK; ++ck) {
        if (wv == 0) {
            if (ck + 1 < NCHUNK) PRODUCE(ck + 1);
        } else if (wv == 1) {
            if (ck < NCHUNK) {
                const int b = ck & 1;
                cp0[b][lane] = c;            // incoming c for this chunk
#pragma unroll
                for (int s = 0; s < CHUNK; ++s) {
                    float u0  = b2f(r01[b][0][s][lane]);
                    float u1n = b2f(r01[b][1][s][lane]);
                    float f = __builtin_amdgcn_rcpf(
                        1.f + exp2_hw(fmaf(c, fwn, u1n)));
                    c = fmaf(c - u0, f, u0);
                    cr[b][s][lane] = c;
                }
            }
        } else {
            if (ck >= 1) {
                const int fk = ck - 1;
                const int bc = fk & 1, b3 = fk % 3;
                const int sb = (wv - 2) * 16;
                const size_t tb = (size_t)fk * CHUNK;
                float cp = (sb == 0) ? cp0[bc][lane] : cr[bc][15][lane];
#pragma unroll
                for (int s2 = 0; s2 < 16; ++s2) {
                    int s = sb + s2;
                    float cc  = cr[bc][s][lane];          // c_new at step s
                    float u2n = b2f(r23[b3][0][s][lane]);
                    float xf  = b2f(r23[b3][1][s][lane]);
                    float r = __builtin_amdgcn_rcpf(
                        1.f + exp2_hw(fmaf(cp, rwn, u2n)));   // r uses c_prev
                    ho[(tb + s) * BD] = fmaf(cc - xf, r, xf); // h uses c_new
                    cp = cc;
                }
            }
        }
        __syncthreads();
    }

    if (wv == 1) out[(size_t)L_DIM * BD + chain] = c;
}

// ---------- launch ----------
extern "C" void kernel_launch(void* const* d_in, const int* in_sizes, int n_in,
                              void* d_out, int out_size, void* d_ws, size_t ws_size,
                              hipStream_t stream) {
    const float* x      = (const float*)d_in[0];
    const float* weight = (const float*)d_in[1];
    const float* wc     = (const float*)d_in[2];
    const float* bias   = (const float*)d_in[3];
    const float* cinit  = (const float*)d_in[4];
    float* out = (float*)d_out;

    // ws layout (bf16 elems): xb[PLANE] | U0|U1n|U2n [3*PLANE] | wt[786432]
    ushort_t* ws = (ushort_t*)d_ws;
    ushort_t* xb = ws;
    ushort_t* U  = ws + PLANE;           // 3 contiguous planes
    ushort_t* wt = ws + 4 * PLANE;

    k_convert_x<<<4096, 256, 0, stream>>>((const float4*)x, (ushort4*)xb);
    k_prep_w<<<(N_DIM * K_DIM) / 256, 256, 0, stream>>>(weight, wt);
    k_gemm8p<<<1536, 512, 0, stream>>>(xb, wt, bias, U);
    k_scan2<<<BD / 64, 256, 0, stream>>>(U, xb, wc, cinit, out);
}

// Round 13
// 260.486 us; speedup vs baseline: 1.1978x; 1.1521x over previous
//
#include <hip/hip_runtime.h>
#include <hip/hip_bf16.h>
#include <stdint.h>

typedef __attribute__((ext_vector_type(4))) float f32x4;
typedef __attribute__((ext_vector_type(8))) short short8;
typedef unsigned int u32;
typedef unsigned short ushort_t;

#define L_DIM 2048
#define B_DIM 32
#define D_DIM 512
#define M_DIM (L_DIM * B_DIM)       // 65536
#define N_DIM (3 * D_DIM)           // 1536
#define K_DIM D_DIM                 // 512
#define BD    (B_DIM * D_DIM)       // 16384
#define PLANE ((size_t)M_DIM * D_DIM)  // 33554432 elems per U plane
#define CHUNK 32
#define NCHUNK (L_DIM / CHUNK)      // 64
#define LOG2E 1.4426950408889634f

// ---------- helpers ----------
__device__ inline ushort_t f2bf(float f) {
    uint32_t u = __float_as_uint(f);
    u += 0x7FFFu + ((u >> 16) & 1u);   // RNE
    return (ushort_t)(u >> 16);
}
__device__ inline float b2f(ushort_t h) {
    return __uint_as_float(((uint32_t)h) << 16);
}
__device__ inline float exp2_hw(float x) {
    float r;
    asm("v_exp_f32 %0, %1" : "=v"(r) : "v"(x));
    return r;
}
__device__ inline void gll16(const ushort_t* g, ushort_t* l) {
    __builtin_amdgcn_global_load_lds(
        (const __attribute__((address_space(1))) u32*)g,
        (__attribute__((address_space(3))) u32*)l,
        16, 0, 0);
}

// ---------- kernel 1: fused prep ----------
// part A: weight (D,3D) f32 -> wt [N][K] bf16, gate-deinterleaved; gate
//         planes (g>=1) pre-scaled by -log2e so the scan sigmoid is pure exp2.
// part B: x f32 -> bf16 (grid-stride float4).
__global__ void k_prep(const float4* __restrict__ x, ushort4* __restrict__ xb,
                       const float* __restrict__ w, ushort_t* __restrict__ wt) {
    int i = blockIdx.x * blockDim.x + threadIdx.x;
    if (i < N_DIM * K_DIM) {             // weight prep (first 786432 threads)
        int k = i & 511;
        int n = i >> 9;
        int dcol = (n & 511) * 3 + (n >> 9);
        float sc = (n >> 9) ? -LOG2E : 1.0f;
        wt[i] = f2bf(w[(size_t)k * N_DIM + dcol] * sc);
    }
    const int stride = gridDim.x * blockDim.x;
    const int n4 = M_DIM * D_DIM / 4;    // 8388608
    for (int j = i; j < n4; j += stride) {
        float4 v = x[j];
        ushort4 o;
        o.x = f2bf(v.x); o.y = f2bf(v.y); o.z = f2bf(v.z); o.w = f2bf(v.w);
        xb[j] = o;
    }
}

// ---------- kernel 2: GEMM (round-3 verified structure, 153us) ----------
// 128x128 tile, 4 waves, BK=64, gll16 staging, XOR swizzle, XCD-chunked grid.
// Weight already prescaled, so epilogue is acc + prescaled bias (one fma).
__global__ __launch_bounds__(256) void k_gemm(
    const ushort_t* __restrict__ Ag,   // [M,K] bf16
    const ushort_t* __restrict__ Wt,   // [N,K] bf16 (gate planes prescaled)
    const float*    __restrict__ bias, // [2D]
    ushort_t*       __restrict__ U)    // 3 planes of [M,D] bf16
{
    __shared__ ushort_t As[128 * 64];
    __shared__ ushort_t Bs[128 * 64];
    const int tid  = threadIdx.x;
    const int lane = tid & 63;
    const int w    = tid >> 6;
    const int wm   = w >> 1, wn = w & 1;

    // XCD-chunked swizzle: 6144 blocks, 8 XCDs, 768 per XCD (bijective).
    const int i   = blockIdx.x;
    const int nb  = (i & 7) * 768 + (i >> 3);
    const int bx  = nb % 12;             // N tile (innermost -> A reuse)
    const int by  = nb / 12;             // M strip
    const int bn0 = bx * 128;
    const int bm0 = by * 128;

    f32x4 acc[4][4] = {};

    for (int kt = 0; kt < K_DIM / 64; ++kt) {
        if (kt) __syncthreads();
#pragma unroll
        for (int it = 0; it < 4; ++it) {
            int c   = it * 256 + tid;
            int row = c >> 3;
            int cin = (c & 7) ^ (row & 7);
            const ushort_t* ga = Ag + (size_t)(bm0 + row) * K_DIM + kt * 64 + cin * 8;
            const ushort_t* gb = Wt + (size_t)(bn0 + row) * K_DIM + kt * 64 + cin * 8;
            int chunkbase = it * 256 + w * 64;   // wave-uniform
            gll16(ga, As + chunkbase * 8);
            gll16(gb, Bs + chunkbase * 8);
        }
        __syncthreads();
#pragma unroll
        for (int kk = 0; kk < 2; ++kk) {
            short8 af[4], bfr[4];
#pragma unroll
            for (int m = 0; m < 4; ++m) {
                int row  = wm * 64 + m * 16 + (lane & 15);
                int byte = (row * 128 + kk * 64 + ((lane >> 4) * 16)) ^ ((row & 7) << 4);
                af[m] = *(const short8*)((const char*)As + byte);
            }
#pragma unroll
            for (int n = 0; n < 4; ++n) {
                int row  = wn * 64 + n * 16 + (lane & 15);
                int byte = (row * 128 + kk * 64 + ((lane >> 4) * 16)) ^ ((row & 7) << 4);
                bfr[n] = *(const short8*)((const char*)Bs + byte);
            }
#pragma unroll
            for (int m = 0; m < 4; ++m)
#pragma unroll
                for (int n = 0; n < 4; ++n)
                    acc[m][n] = __builtin_amdgcn_mfma_f32_16x16x32_bf16(
                        af[m], bfr[n], acc[m][n], 0, 0, 0);
        }
    }

    // epilogue: C/D layout col=lane&15, row=(lane>>4)*4+q (m89-verified)
    const int g  = bn0 >> 9;               // plane (block fully inside one plane)
    const int db = (bn0 & 511) + wn * 64;  // d base in plane
    ushort_t* Up = U + (size_t)g * PLANE;
#pragma unroll
    for (int n = 0; n < 4; ++n) {
        int col = db + n * 16 + (lane & 15);
        float ba = 0.f;
        if (g) ba = -LOG2E * bias[(g - 1) * 512 + col];   // prescaled bias
#pragma unroll
        for (int m = 0; m < 4; ++m) {
            int row0 = bm0 + wm * 64 + m * 16 + ((lane >> 4) * 4);
#pragma unroll
            for (int q = 0; q < 4; ++q) {
                Up[(size_t)(row0 + q) * D_DIM + col] = f2bf(acc[m][n][q] + ba);
            }
        }
    }
}

// ---------- kernel 3: role-split scan (round-10 verified, ~70us) ----------
// wave 0: producer (gll16 staging of u0,u1n,u2n,x)
// wave 1: serial c-chain ONLY, writes incoming c (cp0) + per-step NEW c (cr)
// waves 2-3: finishers — r from c_prev, h from c_new, parallel over t (lag 1)
__global__ __launch_bounds__(256) void k_scan2(
    const ushort_t* __restrict__ U,    // planes: u0 | u1n | u2n  [t*32+b][d]
    const ushort_t* __restrict__ xb,   // [t*32+b][d]
    const float*    __restrict__ wc,   // weight_c [2D]
    const float*    __restrict__ cin,  // c_init [B,D]
    float*          __restrict__ out)  // h [L,B,D] f32, then c_last [B,D]
{
    __shared__ ushort_t r01[2][2][CHUNK][64];  // u0,u1n ring (16 KB)
    __shared__ ushort_t r23[3][2][CHUNK][64];  // u2n,x ring, 3-deep (24 KB)
    __shared__ float    cr[2][CHUNK][64];      // c_new ring (16 KB)
    __shared__ float    cp0[2][64];            // chunk-incoming c (512 B)

    const int tid  = threadIdx.x;
    const int lane = tid & 63;
    const int wv   = tid >> 6;               // 0 prod, 1 chain, 2-3 finish
    const int cb   = blockIdx.x * 64;        // chain base

    const int srow = lane >> 3;
    const int scol = (lane & 7) * 8;
    const ushort_t* s0 = U + cb + scol;
    const ushort_t* s1 = U + PLANE + cb + scol;
    const ushort_t* s2 = U + 2 * PLANE + cb + scol;
    const ushort_t* s3 = xb + cb + scol;

    const int chain = cb + lane;
    const int d     = chain & 511;
    float fwn = 0.f, c = 0.f, rwn = 0.f;
    if (wv == 1) { fwn = -LOG2E * wc[d]; c = cin[chain]; }
    if (wv >= 2) { rwn = -LOG2E * wc[512 + d]; }
    float* ho = out + chain;

#define PRODUCE(CK)                                                            \
    do {                                                                       \
        const size_t t0_ = (size_t)(CK) * CHUNK + srow;                        \
        const int nb_ = (CK) & 1, nc_ = (CK) % 3;                              \
        _Pragma("unroll")                                                      \
        for (int q = 0; q < 4; ++q) {                                          \
            gll16(s0 + (t0_ + q * 8) * BD, &r01[nb_][0][q * 8][0]);            \
            gll16(s1 + (t0_ + q * 8) * BD, &r01[nb_][1][q * 8][0]);            \
            gll16(s2 + (t0_ + q * 8) * BD, &r23[nc_][0][q * 8][0]);            \
            gll16(s3 + (t0_ + q * 8) * BD, &r23[nc_][1][q * 8][0]);            \
        }                                                                      \
    } while (0)

    if (wv == 0) PRODUCE(0);
    __syncthreads();

    for (int ck = 0; ck <= NCHUNK; ++ck) {
        if (wv == 0) {
            if (ck + 1 < NCHUNK) PRODUCE(ck + 1);
        } else if (wv == 1) {
            if (ck < NCHUNK) {
                const int b = ck & 1;
                cp0[b][lane] = c;            // incoming c for this chunk
#pragma unroll
                for (int s = 0; s < CHUNK; ++s) {
                    float u0  = b2f(r01[b][0][s][lane]);
                    float u1n = b2f(r01[b][1][s][lane]);
                    float f = __builtin_amdgcn_rcpf(
                        1.f + exp2_hw(fmaf(c, fwn, u1n)));
                    c = fmaf(c - u0, f, u0);
                    cr[b][s][lane] = c;
                }
            }
        } else {
            if (ck >= 1) {
                const int fk = ck - 1;
                const int bc = fk & 1, b3 = fk % 3;
                const int sb = (wv - 2) * 16;
                const size_t tb = (size_t)fk * CHUNK;
                float cp = (sb == 0) ? cp0[bc][lane] : cr[bc][15][lane];
#pragma unroll
                for (int s2 = 0; s2 < 16; ++s2) {
                    int s = sb + s2;
                    float cc  = cr[bc][s][lane];          // c_new at step s
                    float u2n = b2f(r23[b3][0][s][lane]);
                    float xf  = b2f(r23[b3][1][s][lane]);
                    float r = __builtin_amdgcn_rcpf(
                        1.f + exp2_hw(fmaf(cp, rwn, u2n)));   // r uses c_prev
                    ho[(tb + s) * BD] = fmaf(cc - xf, r, xf); // h uses c_new
                    cp = cc;
                }
            }
        }
        __syncthreads();
    }

    if (wv == 1) out[(size_t)L_DIM * BD + chain] = c;
}

// ---------- launch ----------
extern "C" void kernel_launch(void* const* d_in, const int* in_sizes, int n_in,
                              void* d_out, int out_size, void* d_ws, size_t ws_size,
                              hipStream_t stream) {
    const float* x      = (const float*)d_in[0];
    const float* weight = (const float*)d_in[1];
    const float* wc     = (const float*)d_in[2];
    const float* bias   = (const float*)d_in[3];
    const float* cinit  = (const float*)d_in[4];
    float* out = (float*)d_out;

    // ws layout (bf16 elems): xb[PLANE] | U0|U1n|U2n [3*PLANE] | wt[786432]
    ushort_t* ws = (ushort_t*)d_ws;
    ushort_t* xb = ws;
    ushort_t* U  = ws + PLANE;           // 3 contiguous planes
    ushort_t* wt = ws + 4 * PLANE;

    k_prep<<<4096, 256, 0, stream>>>((const float4*)x, (ushort4*)xb, weight, wt);
    k_gemm<<<6144, 256, 0, stream>>>(xb, wt, bias, U);
    k_scan2<<<BD / 64, 256, 0, stream>>>(U, xb, wc, cinit, out);
}